// Round 1
// 898.588 us; speedup vs baseline: 1.0863x; 1.0863x over previous
//
#include <hip/hip_runtime.h>
#include <hip/hip_bf16.h>

#define E 64
#define A 8
#define L 2048
#define D 128
#define H 8
#define DK 16
#define C3 386      // 3*D+2
#define CKV 129     // D+1
#define NSEG 4
#define SEG 512
#define CH 32       // chunk rows staged per iteration
#define TS 132      // LDS tile row stride in floats (pad +4: 16B-aligned rows, odd
                    // float4-slot stride 33 => conflict-free ds_read_b128/ds_write_b128)
#define WQS 132     // padded LDS stride for wq rows (16B-aligned row base)

// workspace layout (float offsets)  — total ~2.87M floats = 11.5 MB
#define OFF_WQC 0                              // Wq_comb [386][128]
#define OFF_WKC (OFF_WQC + C3*D)               // Wk_comb [129][128]
#define OFF_WVC (OFF_WKC + CKV*D)              // Wv_comb [129][128]
#define OFF_WOV (OFF_WVC + CKV*D)              // Wov     [8][129][128]
#define OFF_WQE (OFF_WOV + H*CKV*D)            // wq_eff  [512][8][129]
#define OFF_PART (OFF_WQE + E*A*H*CKV)         // partials[2048][8h][130]
#define PART_STRIDE (H*130)

// ---- kernel 1: combined projection weights Wq_comb / Wk_comb / Wv_comb ----
// comb[c, h*16+k] = sum_d proj[c,d] * Whead[h,d,k]
__global__ void k_combs(const float* __restrict__ Wq_proj,
                        const float* __restrict__ Wk_proj,
                        const float* __restrict__ Wv_proj,
                        const float* __restrict__ Wq,
                        const float* __restrict__ Wk,
                        const float* __restrict__ Wv,
                        float* __restrict__ ws) {
    int idx = blockIdx.x * 256 + threadIdx.x;
    const float* proj; const float* wh; float* dst;
    if (idx < C3*D)                { proj = Wq_proj; wh = Wq; dst = ws + OFF_WQC; }
    else if (idx < C3*D + CKV*D)   { idx -= C3*D; proj = Wk_proj; wh = Wk; dst = ws + OFF_WKC; }
    else if (idx < C3*D + 2*CKV*D) { idx -= C3*D + CKV*D; proj = Wv_proj; wh = Wv; dst = ws + OFF_WVC; }
    else return;
    int li = idx;
    int c = li >> 7, j = li & 127, h = j >> 4, k = j & 15;
    float s = 0.f;
    #pragma unroll 4
    for (int d = 0; d < D; ++d)
        s += proj[c*D + d] * wh[(h*D + d)*DK + k];
    dst[li] = s;
}

// ---- kernel 2: Wov[h,c,d] = sum_k Wv_comb[c,h*16+k] * Wo[h,k,d] ----
__global__ void k_wov(const float* __restrict__ Wo, float* __restrict__ ws) {
    int idx = blockIdx.x * 256 + threadIdx.x;
    if (idx >= H*CKV*D) return;
    int h = idx / (CKV*D);
    int r = idx % (CKV*D);
    int c = r >> 7, d = r & 127;
    const float* wvc = ws + OFF_WVC;
    float s = 0.f;
    #pragma unroll
    for (int k = 0; k < DK; ++k)
        s += wvc[c*D + h*DK + k] * Wo[(h*DK + k)*D + d];
    ws[OFF_WOV + idx] = s;
}

// ---- kernel 3: per (e,a): qh = q_in @ Wq_comb; wq_eff[h,c] = sum_k qh[h16+k]*Wk_comb[c,h16+k]
__global__ void k_query(const float* __restrict__ graph,
                        const float* __restrict__ depot,
                        const float* __restrict__ tbd,
                        const float* __restrict__ load,
                        float* __restrict__ ws) {
    __shared__ float qin[C3];
    __shared__ float qh[D];
    int ea = blockIdx.x; int e = ea >> 3; int a = ea & 7;
    int t = threadIdx.x;  // 128 threads
    for (int c = t; c < C3; c += 128) {
        float v;
        if (c < 128) v = graph[e*D + c];
        else if (c < 256) v = depot[e*D + c - 128];
        else if (c < 384) v = tbd[e*D + c - 256];
        else if (c == 384) v = load[ea];
        else v = (float)a;
        qin[c] = v;
    }
    __syncthreads();
    const float* wqc = ws + OFF_WQC;
    float s = 0.f;
    #pragma unroll 2
    for (int c = 0; c < C3; ++c) s += qin[c] * wqc[c*D + t];
    qh[t] = s;
    __syncthreads();
    const float* wkc = ws + OFF_WKC;
    float* wqe = ws + OFF_WQE + (size_t)ea * (H*CKV);
    for (int o = t; o < H*CKV; o += 128) {
        int h = o / CKV; int c = o % CKV;
        const float* q8 = qh + h*DK;
        const float* wc = wkc + c*D + h*DK;
        float v = 0.f;
        #pragma unroll
        for (int k = 0; k < DK; ++k) v += q8[k] * wc[k];
        wqe[o] = v;
    }
}

// ---- kernel 4: flash-decoding partials over one 512-position segment ----
__global__ __launch_bounds__(256)
void k_attn(const float* __restrict__ emb,
            const int* __restrict__ lens,
            float* __restrict__ ws) {
    int bid = blockIdx.x;
    int ea = bid >> 2, seg = bid & 3;
    int len = lens[ea];
    int seg0 = seg * SEG;
    float* part = ws + OFF_PART + (size_t)bid * PART_STRIDE;
    int t = threadIdx.x;
    if (seg0 >= len) {  // fully masked segment: neutral partial
        for (int i = t; i < H*130; i += 256)
            part[i] = ((i % 130) == 0) ? -3.0e38f : 0.f;
        return;
    }
    int valid = min(SEG, len - seg0);

    __shared__ __align__(16) float wq[H*WQS];
    __shared__ __align__(16) float tile[CH*TS];
    __shared__ float ptile[H*CH];
    __shared__ float mh[H], Sh[H], alph[H], cmax[H];

    const float* wqe = ws + OFF_WQE + (size_t)ea * (H*CKV);
    for (int i = t; i < H*CKV; i += 256) {
        int hh = i / CKV, cc = i - hh*CKV;
        wq[hh*WQS + cc] = wqe[i];
    }
    if (t < H) { mh[t] = -3.0e38f; Sh[t] = 0.f; }

    int a = ea & 7;
    int h = t >> 5, l = t & 31;   // score ownership: (head, row)
    int c0 = t & 31;              // acc ownership: head h, cols {4c0 .. 4c0+3}
    float4 acc; acc.x = 0.f; acc.y = 0.f; acc.z = 0.f; acc.w = 0.f;

    const float* ebase = emb + (size_t)ea * L * D + (size_t)seg0 * D;
    int nch = (valid + CH - 1) / CH;
    for (int ci = 0; ci < nch; ++ci) {
        int r0 = ci * CH;
        int nr = min(CH, valid - r0);
        __syncthreads();  // protect tile/ptile from previous iteration readers
        // stage nr rows (float4 = 16B/lane) into padded-stride LDS (b128 writes)
        for (int i4 = t; i4 < nr * (D/4); i4 += 256) {
            int lr = i4 >> 5;
            int cc4 = i4 & 31;
            float4 u = *(const float4*)(ebase + (size_t)(r0 + lr) * D + 4*cc4);
            *(float4*)(tile + lr*TS + 4*cc4) = u;
        }
        __syncthreads();
        // scores: s[h][l] = 0.25 * (emb[l]·wq[h] + a*wq[h][128])
        // float4 LDS reads, 4 independent FMA chains
        float s;
        if (l < nr) {
            const float4* er4 = (const float4*)(tile + l*TS);
            const float4* wr4 = (const float4*)(wq + h*WQS);
            float d0 = 0.f, d1 = 0.f, d2 = 0.f, d3 = 0.f;
            #pragma unroll 8
            for (int c4 = 0; c4 < 32; ++c4) {
                float4 ev = er4[c4];
                float4 wv = wr4[c4];
                d0 += ev.x * wv.x; d1 += ev.y * wv.y;
                d2 += ev.z * wv.z; d3 += ev.w * wv.w;
            }
            s = 0.25f * (((d0 + d1) + (d2 + d3)) + (float)a * wq[h*WQS + 128]);
        } else s = -3.0e38f;
        // per-head chunk max (butterfly within the 32-lane group)
        float m = s;
        #pragma unroll
        for (int off = 16; off >= 1; off >>= 1)
            m = fmaxf(m, __shfl_xor(m, off));
        if (l == 0) cmax[h] = m;
        __syncthreads();
        if (t < H) {
            float mo = mh[t];
            float mn = fmaxf(mo, cmax[t]);
            alph[t] = __expf(mo - mn);
            mh[t] = mn;
        }
        __syncthreads();
        float p = (l < nr) ? __expf(s - mh[h]) : 0.f;
        ptile[h*CH + l] = p;
        float ps = p;
        #pragma unroll
        for (int off = 16; off >= 1; off >>= 1)
            ps += __shfl_xor(ps, off);
        if (l == 0) Sh[h] = Sh[h] * alph[h] + ps;
        __syncthreads();
        // accumulate wctx: acc[h][4c0..4c0+3] = acc*alpha + sum_l p[h][l]*emb[l][4c0..]
        // one b128 read per row (conflict-free: slot stride 33 per row)
        float al = alph[h];
        acc.x *= al; acc.y *= al; acc.z *= al; acc.w *= al;
        const float* pt = ptile + h*CH;
        const float* tb = tile + 4*c0;
        #pragma unroll 4
        for (int lr = 0; lr < nr; ++lr) {
            float pv = pt[lr];
            float4 ev = *(const float4*)(tb + lr*TS);
            acc.x += pv * ev.x; acc.y += pv * ev.y;
            acc.z += pv * ev.z; acc.w += pv * ev.w;
        }
    }
    __syncthreads();
    if (t < H) { part[t*130 + 0] = mh[t]; part[t*130 + 1] = Sh[t]; }
    // col 4c0+j stored at offset 2 + 4c0 + j  (same layout as before; k_out unchanged)
    float* pa = part + h*130 + 2 + 4*c0;
    pa[0] = acc.x; pa[1] = acc.y; pa[2] = acc.z; pa[3] = acc.w;
}

// ---- kernel 5: combine segments + output projection, emit fp32 ----
__global__ void k_out(const float* __restrict__ ws, float* __restrict__ out) {
    int ea = blockIdx.x; int a = ea & 7;
    int t = threadIdx.x;  // 128
    __shared__ float fac[H*NSEG];
    __shared__ float sinv[H];
    __shared__ float wctx[H*D];
    const float* part = ws + OFF_PART + (size_t)ea * NSEG * PART_STRIDE;
    if (t < H) {
        float M = -3.0e38f;
        for (int s = 0; s < NSEG; ++s)
            M = fmaxf(M, part[s*PART_STRIDE + t*130]);
        float St = 0.f;
        for (int s = 0; s < NSEG; ++s) {
            float f = __expf(part[s*PART_STRIDE + t*130] - M);
            fac[t*NSEG + s] = f;
            St += part[s*PART_STRIDE + t*130 + 1] * f;
        }
        sinv[t] = 1.f / St;
    }
    __syncthreads();
    for (int i = t; i < H*D; i += 128) {
        int h = i >> 7, c = i & 127;
        float w = 0.f;
        #pragma unroll
        for (int s = 0; s < NSEG; ++s)
            w += part[s*PART_STRIDE + h*130 + 2 + c] * fac[h*NSEG + s];
        wctx[i] = w * sinv[h];
    }
    __syncthreads();
    const float* wov = ws + OFF_WOV;
    float r = 0.f;
    for (int hh = 0; hh < H; ++hh) {
        const float* wr = wov + (size_t)(hh*CKV) * D + t;  // Wov[hh][c][t]
        const float* wc = wctx + hh*D;
        #pragma unroll 4
        for (int c = 0; c < D; ++c) r += wc[c] * wr[c*D];
        r += (float)a * wr[D*D];  // constant agent-id column: wctx[hh][128] == a
    }
    out[ea*D + t] = r;  // fp32 output per reference dtype
}

extern "C" void kernel_launch(void* const* d_in, const int* in_sizes, int n_in,
                              void* d_out, int out_size, void* d_ws, size_t ws_size,
                              hipStream_t stream) {
    const float* graph   = (const float*)d_in[0];
    const float* depot   = (const float*)d_in[1];
    const float* tbd     = (const float*)d_in[2];
    const float* load    = (const float*)d_in[3];
    const float* emb     = (const float*)d_in[4];
    const int*   lens    = (const int*)d_in[5];
    const float* Wq_proj = (const float*)d_in[6];
    const float* Wk_proj = (const float*)d_in[7];
    const float* Wv_proj = (const float*)d_in[8];
    const float* Wq      = (const float*)d_in[9];
    const float* Wk      = (const float*)d_in[10];
    const float* Wv      = (const float*)d_in[11];
    const float* Wo      = (const float*)d_in[12];
    float* ws = (float*)d_ws;
    float* out = (float*)d_out;

    hipLaunchKernelGGL(k_combs, dim3((C3*D + 2*CKV*D + 255)/256), dim3(256), 0, stream,
                       Wq_proj, Wk_proj, Wv_proj, Wq, Wk, Wv, ws);
    hipLaunchKernelGGL(k_wov, dim3((H*CKV*D + 255)/256), dim3(256), 0, stream, Wo, ws);
    hipLaunchKernelGGL(k_query, dim3(E*A), dim3(128), 0, stream, graph, depot, tbd, load, ws);
    hipLaunchKernelGGL(k_attn, dim3(E*A*NSEG), dim3(256), 0, stream, emb, lens, ws);
    hipLaunchKernelGGL(k_out, dim3(E*A), dim3(128), 0, stream, ws, out);
}